// Round 5
// baseline (78.160 us; speedup 1.0000x reference)
//
#include <hip/hip_runtime.h>
#include <math.h>

#define B 512
#define D 256
#define MARGIN 0.3f
#define UW 0.05f
#define MIN_U 1e-6f
#define EPS 1e-8f

#define TI 16    // anchor rows per tile
#define TJ 64    // candidate cols per tile
#define BK 128   // k-chunk (2 chunks cover D=256)
#define NJT (B / TJ)   // 8 j-tiles
#define MAGIC 0x13579BDFu

typedef unsigned long long ull;

// ws layout (no init required; flags compare against MAGIC != 0xAAAAAAAA poison):
//   [0,      32768)  ull  pmax_part[NJT][B]
//   [32768,  65536)  ull  nmin_part[NJT][B]
//   [65536,  66560)  uint flags[256]        (tile-done, MAGIC when ready)
//   [66560,  67328)  float blk_part[64][3]  (loss_sum, n_valid, u_sum)
//   [67328,  67584)  uint blk_flags[64]     (finalize-done, MAGIC when ready)

static __device__ inline ull shfl_xor_u64(ull v, int m) {
    unsigned int lo = (unsigned int)v;
    unsigned int hi = (unsigned int)(v >> 32);
    lo = __shfl_xor(lo, m, 64);
    hi = __shfl_xor(hi, m, 64);
    return ((ull)hi << 32) | lo;
}

static __device__ inline ull bcast_u64_lane0(ull v) {
    unsigned int lo = (unsigned int)v;
    unsigned int hi = (unsigned int)(v >> 32);
    lo = (unsigned int)__shfl((int)lo, 0, 64);
    hi = (unsigned int)__shfl((int)hi, 0, 64);
    return ((ull)hi << 32) | lo;
}

__global__ __launch_bounds__(256) void triplet_fused(const float* __restrict__ emb,
                                                     const float* __restrict__ unc,
                                                     const int* __restrict__ labels,
                                                     ull* __restrict__ pmax_part,
                                                     ull* __restrict__ nmin_part,
                                                     unsigned int* __restrict__ flags,
                                                     float* __restrict__ blk_part,
                                                     unsigned int* __restrict__ blk_flags,
                                                     float* __restrict__ out) {
    const int bid = blockIdx.x;      // 0..255
    const int jt = bid & 7;          // 0..7
    const int it = bid >> 3;         // 0..31
    const int t  = threadIdx.x;
    const int row  = t >> 4;         // 0..15
    const int col4 = (t & 15) * 4;

    __shared__ float As[BK][TI + 1];
    __shared__ float Bs[BK][TJ + 4];
    __shared__ int labI[TI], labJ[TJ];
    __shared__ float red[4][3];

    const int gi0 = it * TI;
    const int gj0 = jt * TJ;
    if (t < TI) labI[t] = labels[gi0 + t];
    if (t < TJ) labJ[t] = labels[gj0 + t];

    // ---- Phase 1: distance tile + hardest-pos/neg mining ----
    // Prefetch BOTH k-chunks into registers up-front (20 float4 in flight).
    float4 apre[2][2];
    float4 bpre[2][8];
#pragma unroll
    for (int c = 0; c < 2; ++c) {
        const int kc = c * BK;
#pragma unroll
        for (int q = 0; q < 2; ++q) {
            const int idx = q * 256 + t;
            const int r = idx >> 5, f = idx & 31;
            apre[c][q] = *reinterpret_cast<const float4*>(&emb[(size_t)(gi0 + r) * D + kc + f * 4]);
        }
#pragma unroll
        for (int g = 0; g < 8; ++g) {
            const int idx = g * 256 + t;
            const int r = idx >> 5, f = idx & 31;
            bpre[c][g] = *reinterpret_cast<const float4*>(&emb[(size_t)(gj0 + r) * D + kc + f * 4]);
        }
    }

    float a0 = 0.f, a1 = 0.f, a2 = 0.f, a3 = 0.f;
#pragma unroll
    for (int c = 0; c < 2; ++c) {
        if (c) __syncthreads();   // protect LDS overwrite vs previous compute
#pragma unroll
        for (int q = 0; q < 2; ++q) {
            const int idx = q * 256 + t;
            const int r = idx >> 5, f = idx & 31;
            float4 v = apre[c][q];
            As[f * 4 + 0][r] = v.x;
            As[f * 4 + 1][r] = v.y;
            As[f * 4 + 2][r] = v.z;
            As[f * 4 + 3][r] = v.w;
        }
#pragma unroll
        for (int g = 0; g < 8; ++g) {
            const int idx = g * 256 + t;
            const int r = idx >> 5, f = idx & 31;
            float4 v = bpre[c][g];
            Bs[f * 4 + 0][r] = v.x;
            Bs[f * 4 + 1][r] = v.y;
            Bs[f * 4 + 2][r] = v.z;
            Bs[f * 4 + 3][r] = v.w;
        }
        __syncthreads();
#pragma unroll 8
        for (int k = 0; k < BK; ++k) {
            float a = As[k][row];
            float4 b = *reinterpret_cast<const float4*>(&Bs[k][col4]);
            float d;
            d = a - b.x; a0 = fmaf(d, d, a0);
            d = a - b.y; a1 = fmaf(d, d, a1);
            d = a - b.z; a2 = fmaf(d, d, a2);
            d = a - b.w; a3 = fmaf(d, d, a3);
        }
    }

    const int gi = gi0 + row;
    const int li = labI[row];
    ull pbest = 0ull;
    ull nbest = ~0ull;
    float accs[4] = {a0, a1, a2, a3};
#pragma unroll
    for (int c = 0; c < 4; ++c) {
        const int jj = col4 + c;
        const int gj = gj0 + jj;
        const float dist = sqrtf(accs[c]) + EPS;
        const int lj = labJ[jj];
        const ull fb = (ull)__float_as_uint(dist) << 32;
        if (li == lj && gi != gj) {
            ull e = fb | (unsigned int)(0xFFFFFFFFu - (unsigned int)gj);
            pbest = pbest > e ? pbest : e;   // larger dist wins; tie -> smaller j
        }
        if (li != lj) {
            ull e = fb | (unsigned int)gj;
            nbest = nbest < e ? nbest : e;   // smaller dist wins; tie -> smaller j
        }
    }
#pragma unroll
    for (int m = 1; m < 16; m <<= 1) {
        ull p2 = shfl_xor_u64(pbest, m);
        ull n2 = shfl_xor_u64(nbest, m);
        pbest = pbest > p2 ? pbest : p2;
        nbest = nbest < n2 ? nbest : n2;
    }
    if ((t & 15) == 0) {
        __hip_atomic_store(&pmax_part[(size_t)jt * B + gi], pbest, __ATOMIC_RELAXED, __HIP_MEMORY_SCOPE_AGENT);
        __hip_atomic_store(&nmin_part[(size_t)jt * B + gi], nbest, __ATOMIC_RELAXED, __HIP_MEMORY_SCOPE_AGENT);
    }
    __syncthreads();
    if (t == 0)
        __hip_atomic_store(&flags[it * 8 + jt], MAGIC, __ATOMIC_RELEASE, __HIP_MEMORY_SCOPE_AGENT);

    // ---- Phase 2: blocks 0..63 finalize 8 anchors each ----
    if (bid < 64) {
        const int it2 = bid >> 1;   // anchors 8*bid..8*bid+7 lie in i-tile bid/2
        if (t == 0) {
            for (int j2 = 0; j2 < NJT; ++j2)
                while (__hip_atomic_load(&flags[it2 * 8 + j2], __ATOMIC_ACQUIRE, __HIP_MEMORY_SCOPE_AGENT) != MAGIC)
                    __builtin_amdgcn_s_sleep(2);
        }
        __syncthreads();

        const int wave = t >> 6;
        const int lane = t & 63;
        float loss_sum = 0.f, nval = 0.f, usum = 0.f;
        const float4* emb4 = reinterpret_cast<const float4*>(emb);
        const float4* unc4 = reinterpret_cast<const float4*>(unc);

#pragma unroll
        for (int a = 0; a < 2; ++a) {
            const int i = bid * 8 + wave * 2 + a;

            ull pe = 0ull, ne = ~0ull;
            if (lane < NJT) {
                pe = __hip_atomic_load(&pmax_part[(size_t)lane * B + i], __ATOMIC_RELAXED, __HIP_MEMORY_SCOPE_AGENT);
                ne = __hip_atomic_load(&nmin_part[(size_t)lane * B + i], __ATOMIC_RELAXED, __HIP_MEMORY_SCOPE_AGENT);
            }
#pragma unroll
            for (int m = 1; m < NJT; m <<= 1) {
                ull p2 = shfl_xor_u64(pe, m);
                ull n2 = shfl_xor_u64(ne, m);
                pe = pe > p2 ? pe : p2;
                ne = ne < n2 ? ne : n2;
            }
            pe = bcast_u64_lane0(pe);
            ne = bcast_u64_lane0(ne);

            const bool valid = (pe != 0ull) && (ne != ~0ull);
            const int jp = valid ? (int)(0xFFFFFFFFu - (unsigned int)pe) : i;
            const int jn = valid ? (int)(unsigned int)ne : i;
            const float dp = __uint_as_float((unsigned int)(pe >> 32));
            const float dn = __uint_as_float((unsigned int)(ne >> 32));

            float4 e = emb4[(size_t)i * 64 + lane];
            float4 u = unc4[(size_t)i * 64 + lane];
            float4 p = emb4[(size_t)jp * 64 + lane];
            float4 n = emb4[(size_t)jn * 64 + lane];
            float ux = fminf(fmaxf(u.x, MIN_U), 1.0f);
            float uy = fminf(fmaxf(u.y, MIN_U), 1.0f);
            float uz = fminf(fmaxf(u.z, MIN_U), 1.0f);
            float uw_ = fminf(fmaxf(u.w, MIN_U), 1.0f);

            float s0, s1, s2, d;
            d = e.x - p.x; s0 = ux * ux * d * d;
            d = e.y - p.y; s0 = fmaf(uy * uy, d * d, s0);
            d = e.z - p.z; s0 = fmaf(uz * uz, d * d, s0);
            d = e.w - p.w; s0 = fmaf(uw_ * uw_, d * d, s0);
            d = e.x - n.x; s1 = ux * ux * d * d;
            d = e.y - n.y; s1 = fmaf(uy * uy, d * d, s1);
            d = e.z - n.z; s1 = fmaf(uz * uz, d * d, s1);
            d = e.w - n.w; s1 = fmaf(uw_ * uw_, d * d, s1);
            s2 = ux + uy + uz + uw_;

#pragma unroll
            for (int m = 1; m < 64; m <<= 1) {
                s0 += __shfl_xor(s0, m, 64);
                s1 += __shfl_xor(s1, m, 64);
                s2 += __shfl_xor(s2, m, 64);
            }

            if (lane == 0) {
                usum += s2;
                if (valid) {
                    const float up2 = s0 / (dp * dp) + EPS;
                    const float un2 = s1 / (dn * dn) + EPS;
                    const float sigma = sqrtf(up2 + un2 + EPS);
                    const float z = (dp - dn + MARGIN + UW * sigma) / sigma;  // T=1
                    const float sp = fmaxf(z, 0.f) + log1pf(expf(-fabsf(z)));
                    loss_sum += sigma * sp;
                    nval += 1.0f;
                }
            }
        }

        if (lane == 0) {
            red[wave][0] = loss_sum;
            red[wave][1] = nval;
            red[wave][2] = usum;
        }
        __syncthreads();
        if (t == 0) {
            float l = red[0][0] + red[1][0] + red[2][0] + red[3][0];
            float v = red[0][1] + red[1][1] + red[2][1] + red[3][1];
            float s = red[0][2] + red[1][2] + red[2][2] + red[3][2];
            __hip_atomic_store(&blk_part[bid * 3 + 0], l, __ATOMIC_RELAXED, __HIP_MEMORY_SCOPE_AGENT);
            __hip_atomic_store(&blk_part[bid * 3 + 1], v, __ATOMIC_RELAXED, __HIP_MEMORY_SCOPE_AGENT);
            __hip_atomic_store(&blk_part[bid * 3 + 2], s, __ATOMIC_RELAXED, __HIP_MEMORY_SCOPE_AGENT);
            __hip_atomic_store(&blk_flags[bid], MAGIC, __ATOMIC_RELEASE, __HIP_MEMORY_SCOPE_AGENT);
        }
    }

    // ---- Phase 3: block 255 wave 0 reduces the 64 block partials ----
    if (bid == 255 && t < 64) {
        while (__hip_atomic_load(&blk_flags[t], __ATOMIC_ACQUIRE, __HIP_MEMORY_SCOPE_AGENT) != MAGIC)
            __builtin_amdgcn_s_sleep(2);
        float l = __hip_atomic_load(&blk_part[t * 3 + 0], __ATOMIC_RELAXED, __HIP_MEMORY_SCOPE_AGENT);
        float v = __hip_atomic_load(&blk_part[t * 3 + 1], __ATOMIC_RELAXED, __HIP_MEMORY_SCOPE_AGENT);
        float s = __hip_atomic_load(&blk_part[t * 3 + 2], __ATOMIC_RELAXED, __HIP_MEMORY_SCOPE_AGENT);
#pragma unroll
        for (int m = 1; m < 64; m <<= 1) {
            l += __shfl_xor(l, m, 64);
            v += __shfl_xor(v, m, 64);
            s += __shfl_xor(s, m, 64);
        }
        if (t == 0) {
            float total = l / fmaxf(v, 1.0f) + UW * (s / (float)(B * D));
            if (!isfinite(total)) total = 0.f;
            out[0] = total;
        }
    }
}

extern "C" void kernel_launch(void* const* d_in, const int* in_sizes, int n_in,
                              void* d_out, int out_size, void* d_ws, size_t ws_size,
                              hipStream_t stream) {
    const float* emb = (const float*)d_in[0];
    const float* unc = (const float*)d_in[1];
    const int* labels = (const int*)d_in[2];
    float* out = (float*)d_out;

    char* ws = (char*)d_ws;
    ull* pmax_part = (ull*)(ws);
    ull* nmin_part = (ull*)(ws + 32768);
    unsigned int* flags = (unsigned int*)(ws + 65536);
    float* blk_part = (float*)(ws + 66560);
    unsigned int* blk_flags = (unsigned int*)(ws + 67328);

    triplet_fused<<<256, 256, 0, stream>>>(emb, unc, labels, pmax_part, nmin_part,
                                           flags, blk_part, blk_flags, out);
}

// Round 6
// 73.530 us; speedup vs baseline: 1.0630x; 1.0630x over previous
//
#include <hip/hip_runtime.h>
#include <math.h>

#define B 512
#define D 256
#define MARGIN 0.3f
#define UW 0.05f
#define MIN_U 1e-6f
#define EPS 1e-8f

#define TI 16   // anchor rows per block
#define TJ 64   // candidate cols per block
#define NJT (B / TJ)   // 8 j-tiles

typedef unsigned long long ull;

// ws layout (no init required -- every slot written before read):
//   [0,      32768)  ull pmax_part[NJT][B]
//   [32768,  65536)  ull nmin_part[NJT][B]
//   [65536,  66304)  float blk_part[64][3]  (loss_sum, n_valid, u_sum)
//   [66304,  66308)  u32 counter   (zeroed by dist_mine block (0,0))

static __device__ inline ull shfl_xor_u64(ull v, int m) {
    unsigned int lo = (unsigned int)v;
    unsigned int hi = (unsigned int)(v >> 32);
    lo = __shfl_xor(lo, m, 64);
    hi = __shfl_xor(hi, m, 64);
    return ((ull)hi << 32) | lo;
}

static __device__ inline ull bcast_u64_lane0(ull v) {
    unsigned int lo = (unsigned int)v;
    unsigned int hi = (unsigned int)(v >> 32);
    lo = (unsigned int)__shfl((int)lo, 0, 64);
    hi = (unsigned int)__shfl((int)hi, 0, 64);
    return ((ull)hi << 32) | lo;
}

__global__ __launch_bounds__(256) void dist_mine(const float* __restrict__ emb,
                                                 const int* __restrict__ labels,
                                                 ull* __restrict__ pmax_part,
                                                 ull* __restrict__ nmin_part,
                                                 unsigned int* __restrict__ counter) {
    const int jt = blockIdx.x;   // 0..7
    const int it = blockIdx.y;   // 0..31
    const int t  = threadIdx.x;
    const int row  = t >> 4;
    const int col4 = (t & 15) * 4;

    if (jt == 0 && it == 0 && t == 0) *counter = 0u;  // init for finalize kernel

    // Full-depth tiles: one staging round, one barrier.  87 KB < 160 KB LDS.
    __shared__ float As[D][TI + 1];   // [k][i]
    __shared__ float Bs[D][TJ + 4];   // [k][j]
    __shared__ int labI[TI], labJ[TJ];

    const int gi0 = it * TI;
    const int gj0 = jt * TJ;
    if (t < TI) labI[t] = labels[gi0 + t];
    if (t < TJ) labJ[t] = labels[gj0 + t];

    // stage A: 16 rows x 64 float4 = 1024 float4, 4 per thread (coalesced)
#pragma unroll
    for (int q = 0; q < 4; ++q) {
        const int idx = q * 256 + t;
        const int r = idx >> 6, f = idx & 63;
        float4 v = *reinterpret_cast<const float4*>(&emb[(size_t)(gi0 + r) * D + f * 4]);
        As[f * 4 + 0][r] = v.x;
        As[f * 4 + 1][r] = v.y;
        As[f * 4 + 2][r] = v.z;
        As[f * 4 + 3][r] = v.w;
    }
    // stage B: 64 rows x 64 float4 = 4096 float4, 16 per thread (coalesced)
#pragma unroll
    for (int g = 0; g < 16; ++g) {
        const int idx = g * 256 + t;
        const int r = idx >> 6, f = idx & 63;
        float4 v = *reinterpret_cast<const float4*>(&emb[(size_t)(gj0 + r) * D + f * 4]);
        Bs[f * 4 + 0][r] = v.x;
        Bs[f * 4 + 1][r] = v.y;
        Bs[f * 4 + 2][r] = v.z;
        Bs[f * 4 + 3][r] = v.w;
    }
    __syncthreads();

    float a0 = 0.f, a1 = 0.f, a2 = 0.f, a3 = 0.f;
#pragma unroll 8
    for (int k = 0; k < D; ++k) {
        float a = As[k][row];
        float4 b = *reinterpret_cast<const float4*>(&Bs[k][col4]);
        float d;
        d = a - b.x; a0 = fmaf(d, d, a0);
        d = a - b.y; a1 = fmaf(d, d, a1);
        d = a - b.z; a2 = fmaf(d, d, a2);
        d = a - b.w; a3 = fmaf(d, d, a3);
    }

    const int gi = gi0 + row;
    const int li = labI[row];
    ull pbest = 0ull;
    ull nbest = ~0ull;
    float accs[4] = {a0, a1, a2, a3};
#pragma unroll
    for (int c = 0; c < 4; ++c) {
        const int jj = col4 + c;
        const int gj = gj0 + jj;
        const float dist = sqrtf(accs[c]) + EPS;
        const int lj = labJ[jj];
        const ull fb = (ull)__float_as_uint(dist) << 32;
        if (li == lj && gi != gj) {
            ull e = fb | (unsigned int)(0xFFFFFFFFu - (unsigned int)gj);
            pbest = pbest > e ? pbest : e;   // larger dist wins; tie -> smaller j
        }
        if (li != lj) {
            ull e = fb | (unsigned int)gj;
            nbest = nbest < e ? nbest : e;   // smaller dist wins; tie -> smaller j
        }
    }
    // reduce across the 16 consecutive lanes sharing this row (xor stays in group)
#pragma unroll
    for (int m = 1; m < 16; m <<= 1) {
        ull p2 = shfl_xor_u64(pbest, m);
        ull n2 = shfl_xor_u64(nbest, m);
        pbest = pbest > p2 ? pbest : p2;
        nbest = nbest < n2 ? nbest : n2;
    }
    if ((t & 15) == 0) {
        pmax_part[(size_t)jt * B + gi] = pbest;
        nmin_part[(size_t)jt * B + gi] = nbest;
    }
}

// 64 blocks x 256 threads; each wave handles 2 anchors (64 blk * 4 waves * 2 = 512).
// Last-done block reduces the 64 per-block partials and writes out[0].
__global__ __launch_bounds__(256) void finalize(const float* __restrict__ emb,
                                                const float* __restrict__ unc,
                                                const ull* __restrict__ pmax_part,
                                                const ull* __restrict__ nmin_part,
                                                float* __restrict__ blk_part,
                                                unsigned int* __restrict__ counter,
                                                float* __restrict__ out) {
    const int t = threadIdx.x;
    const int wave = t >> 6;   // 0..3
    const int lane = t & 63;
    __shared__ float red[4][3];
    __shared__ int s_last;

    float loss_sum = 0.f, nval = 0.f, usum = 0.f;
    const float4* emb4 = reinterpret_cast<const float4*>(emb);
    const float4* unc4 = reinterpret_cast<const float4*>(unc);

#pragma unroll
    for (int a = 0; a < 2; ++a) {
        const int i = blockIdx.x * 8 + wave * 2 + a;

        // reduce the 8 per-jt partials (lanes 0..7 carry real data)
        ull pe = 0ull, ne = ~0ull;
        if (lane < NJT) {
            pe = pmax_part[(size_t)lane * B + i];
            ne = nmin_part[(size_t)lane * B + i];
        }
#pragma unroll
        for (int m = 1; m < NJT; m <<= 1) {
            ull p2 = shfl_xor_u64(pe, m);
            ull n2 = shfl_xor_u64(ne, m);
            pe = pe > p2 ? pe : p2;
            ne = ne < n2 ? ne : n2;
        }
        pe = bcast_u64_lane0(pe);
        ne = bcast_u64_lane0(ne);

        const bool valid = (pe != 0ull) && (ne != ~0ull);
        const int jp = valid ? (int)(0xFFFFFFFFu - (unsigned int)pe) : i;
        const int jn = valid ? (int)(unsigned int)ne : i;
        const float dp = __uint_as_float((unsigned int)(pe >> 32));
        const float dn = __uint_as_float((unsigned int)(ne >> 32));

        // coalesced float4 row reads: lane l covers dims 4l..4l+3
        float4 e = emb4[(size_t)i * 64 + lane];
        float4 u = unc4[(size_t)i * 64 + lane];
        float4 p = emb4[(size_t)jp * 64 + lane];
        float4 n = emb4[(size_t)jn * 64 + lane];
        float ux = fminf(fmaxf(u.x, MIN_U), 1.0f);
        float uy = fminf(fmaxf(u.y, MIN_U), 1.0f);
        float uz = fminf(fmaxf(u.z, MIN_U), 1.0f);
        float uw_ = fminf(fmaxf(u.w, MIN_U), 1.0f);

        float s0, s1, s2, d;
        d = e.x - p.x; s0 = ux * ux * d * d;
        d = e.y - p.y; s0 = fmaf(uy * uy, d * d, s0);
        d = e.z - p.z; s0 = fmaf(uz * uz, d * d, s0);
        d = e.w - p.w; s0 = fmaf(uw_ * uw_, d * d, s0);
        d = e.x - n.x; s1 = ux * ux * d * d;
        d = e.y - n.y; s1 = fmaf(uy * uy, d * d, s1);
        d = e.z - n.z; s1 = fmaf(uz * uz, d * d, s1);
        d = e.w - n.w; s1 = fmaf(uw_ * uw_, d * d, s1);
        s2 = ux + uy + uz + uw_;

#pragma unroll
        for (int m = 1; m < 64; m <<= 1) {
            s0 += __shfl_xor(s0, m, 64);
            s1 += __shfl_xor(s1, m, 64);
            s2 += __shfl_xor(s2, m, 64);
        }

        if (lane == 0) {
            usum += s2;
            if (valid) {
                const float up2 = s0 / (dp * dp) + EPS;
                const float un2 = s1 / (dn * dn) + EPS;
                const float sigma = sqrtf(up2 + un2 + EPS);
                const float z = (dp - dn + MARGIN + UW * sigma) / sigma;  // T=1
                const float sp = fmaxf(z, 0.f) + log1pf(expf(-fabsf(z)));
                loss_sum += sigma * sp;
                nval += 1.0f;
            }
        }
    }

    if (lane == 0) {
        red[wave][0] = loss_sum;
        red[wave][1] = nval;
        red[wave][2] = usum;
    }
    __syncthreads();
    if (t == 0) {
        float l = red[0][0] + red[1][0] + red[2][0] + red[3][0];
        float v = red[0][1] + red[1][1] + red[2][1] + red[3][1];
        float s = red[0][2] + red[1][2] + red[2][2] + red[3][2];
        __hip_atomic_store(&blk_part[blockIdx.x * 3 + 0], l, __ATOMIC_RELAXED, __HIP_MEMORY_SCOPE_AGENT);
        __hip_atomic_store(&blk_part[blockIdx.x * 3 + 1], v, __ATOMIC_RELAXED, __HIP_MEMORY_SCOPE_AGENT);
        __hip_atomic_store(&blk_part[blockIdx.x * 3 + 2], s, __ATOMIC_RELAXED, __HIP_MEMORY_SCOPE_AGENT);
        unsigned int done = __hip_atomic_fetch_add(counter, 1u, __ATOMIC_ACQ_REL, __HIP_MEMORY_SCOPE_AGENT);
        s_last = (done == 63u);
    }
    __syncthreads();

    if (s_last && wave == 0) {
        // last block: reduce the 64 per-block partials
        float l = __hip_atomic_load(&blk_part[lane * 3 + 0], __ATOMIC_RELAXED, __HIP_MEMORY_SCOPE_AGENT);
        float v = __hip_atomic_load(&blk_part[lane * 3 + 1], __ATOMIC_RELAXED, __HIP_MEMORY_SCOPE_AGENT);
        float s = __hip_atomic_load(&blk_part[lane * 3 + 2], __ATOMIC_RELAXED, __HIP_MEMORY_SCOPE_AGENT);
#pragma unroll
        for (int m = 1; m < 64; m <<= 1) {
            l += __shfl_xor(l, m, 64);
            v += __shfl_xor(v, m, 64);
            s += __shfl_xor(s, m, 64);
        }
        if (lane == 0) {
            float total = l / fmaxf(v, 1.0f) + UW * (s / (float)(B * D));
            if (!isfinite(total)) total = 0.f;
            out[0] = total;
        }
    }
}

extern "C" void kernel_launch(void* const* d_in, const int* in_sizes, int n_in,
                              void* d_out, int out_size, void* d_ws, size_t ws_size,
                              hipStream_t stream) {
    const float* emb = (const float*)d_in[0];
    const float* unc = (const float*)d_in[1];
    const int* labels = (const int*)d_in[2];
    float* out = (float*)d_out;

    char* ws = (char*)d_ws;
    ull* pmax_part = (ull*)(ws);
    ull* nmin_part = (ull*)(ws + 32768);
    float* blk_part = (float*)(ws + 65536);
    unsigned int* counter = (unsigned int*)(ws + 66304);

    dim3 grid(NJT, B / TI);   // (8, 32)
    dist_mine<<<grid, 256, 0, stream>>>(emb, labels, pmax_part, nmin_part, counter);
    finalize<<<64, 256, 0, stream>>>(emb, unc, pmax_part, nmin_part, blk_part, counter, out);
}

// Round 7
// 73.071 us; speedup vs baseline: 1.0696x; 1.0063x over previous
//
#include <hip/hip_runtime.h>
#include <math.h>

#define B 512
#define D 256
#define MARGIN 0.3f
#define UW 0.05f
#define MIN_U 1e-6f
#define EPS 1e-8f

#define TI 16   // anchor rows per block
#define TJ 64   // candidate cols per block
#define BK 64   // k-chunk
#define NJT (B / TJ)   // 8 j-tiles

typedef unsigned long long ull;

// ws layout (no init required -- every slot written before read):
//   [0,      32768)  ull pmax_part[NJT][B]
//   [32768,  65536)  ull nmin_part[NJT][B]
//   [65536,  66304)  float blk_part[64][3]  (loss_sum, n_valid, u_sum)
//   [66304,  66308)  u32 counter   (zeroed by dist_mine block (0,0))

static __device__ inline ull shfl_xor_u64(ull v, int m) {
    unsigned int lo = (unsigned int)v;
    unsigned int hi = (unsigned int)(v >> 32);
    lo = __shfl_xor(lo, m, 64);
    hi = __shfl_xor(hi, m, 64);
    return ((ull)hi << 32) | lo;
}

static __device__ inline ull bcast_u64_lane0(ull v) {
    unsigned int lo = (unsigned int)v;
    unsigned int hi = (unsigned int)(v >> 32);
    lo = (unsigned int)__shfl((int)lo, 0, 64);
    hi = (unsigned int)__shfl((int)hi, 0, 64);
    return ((ull)hi << 32) | lo;
}

__global__ __launch_bounds__(256) void dist_mine(const float* __restrict__ emb,
                                                 const int* __restrict__ labels,
                                                 ull* __restrict__ pmax_part,
                                                 ull* __restrict__ nmin_part,
                                                 unsigned int* __restrict__ counter) {
    const int jt = blockIdx.x;   // 0..7
    const int it = blockIdx.y;   // 0..31
    const int t  = threadIdx.x;
    const int row  = t >> 4;
    const int col4 = (t & 15) * 4;

    if (jt == 0 && it == 0 && t == 0) *counter = 0u;  // init for finalize kernel

    __shared__ float As[BK][TI + 1];
    __shared__ float Bs[BK][TJ + 4];
    __shared__ int labI[TI], labJ[TJ];

    const int gi0 = it * TI;
    const int gj0 = jt * TJ;
    if (t < TI) labI[t] = labels[gi0 + t];
    if (t < TJ) labJ[t] = labels[gj0 + t];

    float a0 = 0.f, a1 = 0.f, a2 = 0.f, a3 = 0.f;

    for (int kc = 0; kc < D; kc += BK) {
        __syncthreads();
        {
            const int r = t >> 4;
            const int f = t & 15;
            float4 v = *reinterpret_cast<const float4*>(&emb[(size_t)(gi0 + r) * D + kc + f * 4]);
            As[f * 4 + 0][r] = v.x;
            As[f * 4 + 1][r] = v.y;
            As[f * 4 + 2][r] = v.z;
            As[f * 4 + 3][r] = v.w;
        }
#pragma unroll
        for (int g = 0; g < 4; ++g) {
            const int r = g * 16 + (t >> 4);
            const int f = t & 15;
            float4 v = *reinterpret_cast<const float4*>(&emb[(size_t)(gj0 + r) * D + kc + f * 4]);
            Bs[f * 4 + 0][r] = v.x;
            Bs[f * 4 + 1][r] = v.y;
            Bs[f * 4 + 2][r] = v.z;
            Bs[f * 4 + 3][r] = v.w;
        }
        __syncthreads();
#pragma unroll 8
        for (int k = 0; k < BK; ++k) {
            float a = As[k][row];
            float4 b = *reinterpret_cast<const float4*>(&Bs[k][col4]);
            float d;
            d = a - b.x; a0 = fmaf(d, d, a0);
            d = a - b.y; a1 = fmaf(d, d, a1);
            d = a - b.z; a2 = fmaf(d, d, a2);
            d = a - b.w; a3 = fmaf(d, d, a3);
        }
    }

    const int gi = gi0 + row;
    const int li = labI[row];
    ull pbest = 0ull;
    ull nbest = ~0ull;
    float accs[4] = {a0, a1, a2, a3};
#pragma unroll
    for (int c = 0; c < 4; ++c) {
        const int jj = col4 + c;
        const int gj = gj0 + jj;
        const float dist = sqrtf(accs[c]) + EPS;
        const int lj = labJ[jj];
        const ull fb = (ull)__float_as_uint(dist) << 32;
        if (li == lj && gi != gj) {
            ull e = fb | (unsigned int)(0xFFFFFFFFu - (unsigned int)gj);
            pbest = pbest > e ? pbest : e;   // larger dist wins; tie -> smaller j
        }
        if (li != lj) {
            ull e = fb | (unsigned int)gj;
            nbest = nbest < e ? nbest : e;   // smaller dist wins; tie -> smaller j
        }
    }
    // reduce across the 16 consecutive lanes sharing this row (xor stays in group)
#pragma unroll
    for (int m = 1; m < 16; m <<= 1) {
        ull p2 = shfl_xor_u64(pbest, m);
        ull n2 = shfl_xor_u64(nbest, m);
        pbest = pbest > p2 ? pbest : p2;
        nbest = nbest < n2 ? nbest : n2;
    }
    if ((t & 15) == 0) {
        pmax_part[(size_t)jt * B + gi] = pbest;
        nmin_part[(size_t)jt * B + gi] = nbest;
    }
}

// 64 blocks x 256 threads; each wave handles 2 anchors (64 blk * 4 waves * 2 = 512).
// Last-done block reduces the 64 per-block partials and writes out[0].
__global__ __launch_bounds__(256) void finalize(const float* __restrict__ emb,
                                                const float* __restrict__ unc,
                                                const ull* __restrict__ pmax_part,
                                                const ull* __restrict__ nmin_part,
                                                float* __restrict__ blk_part,
                                                unsigned int* __restrict__ counter,
                                                float* __restrict__ out) {
    const int t = threadIdx.x;
    const int wave = t >> 6;   // 0..3
    const int lane = t & 63;
    __shared__ float red[4][3];
    __shared__ int s_last;

    float loss_sum = 0.f, nval = 0.f, usum = 0.f;
    const float4* emb4 = reinterpret_cast<const float4*>(emb);
    const float4* unc4 = reinterpret_cast<const float4*>(unc);

#pragma unroll
    for (int a = 0; a < 2; ++a) {
        const int i = blockIdx.x * 8 + wave * 2 + a;

        // reduce the 8 per-jt partials (lanes 0..7 carry real data)
        ull pe = 0ull, ne = ~0ull;
        if (lane < NJT) {
            pe = pmax_part[(size_t)lane * B + i];
            ne = nmin_part[(size_t)lane * B + i];
        }
#pragma unroll
        for (int m = 1; m < NJT; m <<= 1) {
            ull p2 = shfl_xor_u64(pe, m);
            ull n2 = shfl_xor_u64(ne, m);
            pe = pe > p2 ? pe : p2;
            ne = ne < n2 ? ne : n2;
        }
        pe = bcast_u64_lane0(pe);
        ne = bcast_u64_lane0(ne);

        const bool valid = (pe != 0ull) && (ne != ~0ull);
        const int jp = valid ? (int)(0xFFFFFFFFu - (unsigned int)pe) : i;
        const int jn = valid ? (int)(unsigned int)ne : i;
        const float dp = __uint_as_float((unsigned int)(pe >> 32));
        const float dn = __uint_as_float((unsigned int)(ne >> 32));

        // coalesced float4 row reads: lane l covers dims 4l..4l+3
        float4 e = emb4[(size_t)i * 64 + lane];
        float4 u = unc4[(size_t)i * 64 + lane];
        float4 p = emb4[(size_t)jp * 64 + lane];
        float4 n = emb4[(size_t)jn * 64 + lane];
        float ux = fminf(fmaxf(u.x, MIN_U), 1.0f);
        float uy = fminf(fmaxf(u.y, MIN_U), 1.0f);
        float uz = fminf(fmaxf(u.z, MIN_U), 1.0f);
        float uw_ = fminf(fmaxf(u.w, MIN_U), 1.0f);

        float s0, s1, s2, d;
        d = e.x - p.x; s0 = ux * ux * d * d;
        d = e.y - p.y; s0 = fmaf(uy * uy, d * d, s0);
        d = e.z - p.z; s0 = fmaf(uz * uz, d * d, s0);
        d = e.w - p.w; s0 = fmaf(uw_ * uw_, d * d, s0);
        d = e.x - n.x; s1 = ux * ux * d * d;
        d = e.y - n.y; s1 = fmaf(uy * uy, d * d, s1);
        d = e.z - n.z; s1 = fmaf(uz * uz, d * d, s1);
        d = e.w - n.w; s1 = fmaf(uw_ * uw_, d * d, s1);
        s2 = ux + uy + uz + uw_;

#pragma unroll
        for (int m = 1; m < 64; m <<= 1) {
            s0 += __shfl_xor(s0, m, 64);
            s1 += __shfl_xor(s1, m, 64);
            s2 += __shfl_xor(s2, m, 64);
        }

        if (lane == 0) {
            usum += s2;
            if (valid) {
                const float up2 = s0 / (dp * dp) + EPS;
                const float un2 = s1 / (dn * dn) + EPS;
                const float sigma = sqrtf(up2 + un2 + EPS);
                const float z = (dp - dn + MARGIN + UW * sigma) / sigma;  // T=1
                const float sp = fmaxf(z, 0.f) + log1pf(expf(-fabsf(z)));
                loss_sum += sigma * sp;
                nval += 1.0f;
            }
        }
    }

    if (lane == 0) {
        red[wave][0] = loss_sum;
        red[wave][1] = nval;
        red[wave][2] = usum;
    }
    __syncthreads();
    if (t == 0) {
        float l = red[0][0] + red[1][0] + red[2][0] + red[3][0];
        float v = red[0][1] + red[1][1] + red[2][1] + red[3][1];
        float s = red[0][2] + red[1][2] + red[2][2] + red[3][2];
        __hip_atomic_store(&blk_part[blockIdx.x * 3 + 0], l, __ATOMIC_RELAXED, __HIP_MEMORY_SCOPE_AGENT);
        __hip_atomic_store(&blk_part[blockIdx.x * 3 + 1], v, __ATOMIC_RELAXED, __HIP_MEMORY_SCOPE_AGENT);
        __hip_atomic_store(&blk_part[blockIdx.x * 3 + 2], s, __ATOMIC_RELAXED, __HIP_MEMORY_SCOPE_AGENT);
        unsigned int done = __hip_atomic_fetch_add(counter, 1u, __ATOMIC_ACQ_REL, __HIP_MEMORY_SCOPE_AGENT);
        s_last = (done == 63u);
    }
    __syncthreads();

    if (s_last && wave == 0) {
        // last block: reduce the 64 per-block partials
        float l = __hip_atomic_load(&blk_part[lane * 3 + 0], __ATOMIC_RELAXED, __HIP_MEMORY_SCOPE_AGENT);
        float v = __hip_atomic_load(&blk_part[lane * 3 + 1], __ATOMIC_RELAXED, __HIP_MEMORY_SCOPE_AGENT);
        float s = __hip_atomic_load(&blk_part[lane * 3 + 2], __ATOMIC_RELAXED, __HIP_MEMORY_SCOPE_AGENT);
#pragma unroll
        for (int m = 1; m < 64; m <<= 1) {
            l += __shfl_xor(l, m, 64);
            v += __shfl_xor(v, m, 64);
            s += __shfl_xor(s, m, 64);
        }
        if (lane == 0) {
            float total = l / fmaxf(v, 1.0f) + UW * (s / (float)(B * D));
            if (!isfinite(total)) total = 0.f;
            out[0] = total;
        }
    }
}

extern "C" void kernel_launch(void* const* d_in, const int* in_sizes, int n_in,
                              void* d_out, int out_size, void* d_ws, size_t ws_size,
                              hipStream_t stream) {
    const float* emb = (const float*)d_in[0];
    const float* unc = (const float*)d_in[1];
    const int* labels = (const int*)d_in[2];
    float* out = (float*)d_out;

    char* ws = (char*)d_ws;
    ull* pmax_part = (ull*)(ws);
    ull* nmin_part = (ull*)(ws + 32768);
    float* blk_part = (float*)(ws + 65536);
    unsigned int* counter = (unsigned int*)(ws + 66304);

    dim3 grid(NJT, B / TI);   // (8, 32)
    dist_mine<<<grid, 256, 0, stream>>>(emb, labels, pmax_part, nmin_part, counter);
    finalize<<<64, 256, 0, stream>>>(emb, unc, pmax_part, nmin_part, blk_part, counter, out);
}